// Round 8
// baseline (100.258 us; speedup 1.0000x reference)
//
#include <hip/hip_runtime.h>

// Chamfer distance: B=8, N=M=8192, D=3, fp32, via bf16 split-precision MFMA.
// R8: R7 was pipe-serialized at 2 waves/SIMD (MFMA 13.7us + VALU 17 + LDS 10
// ~= measured 43.5). Fixes:
//  - MSPLIT=2 -> 1024 blocks = 4 waves/SIMD; merge via atomicMin(ordered u32).
//  - global_load_lds width=16 staging (no register ferry, no SWRITE issue).
//  - m-tile pairs folded with v_min3 (fmin issue 13.7 -> 6.8 us).
// Per-CU budget: MFMA 13.7 (binding) / LDS 10.2 / VALU ~9 -> predict ~18-23us.

#define B_DIM 8
#define N_DIM 8192
#define MT    (N_DIM / 32)      // 256 m-tiles per (dir,b)
#define MSPLIT 2
#define MTB   (MT / MSPLIT)     // 128 m-tiles per block
#define CH    16                // tiles per staged chunk (16 KB)
#define NC    (MTB / CH)        // 8 chunks
#define BLOCK 256
#define PPW   2                 // n-tiles per wave

typedef short  bf16x8 __attribute__((ext_vector_type(8)));
typedef float  f32x16 __attribute__((ext_vector_type(16)));

__device__ __forceinline__ unsigned short bf16_rne(float f) {
    unsigned int u = __float_as_uint(f);
    u += 0x7fffu + ((u >> 16) & 1u);
    return (unsigned short)(u >> 16);
}
__device__ __forceinline__ float bf16f(unsigned short h) {
    return __uint_as_float(((unsigned int)h) << 16);
}
__device__ __forceinline__ unsigned int f32_to_ordered_u32(float f) {
    unsigned int u = __float_as_uint(f);
    return (u & 0x80000000u) ? ~u : (u | 0x80000000u);
}
__device__ __forceinline__ float ordered_u32_to_f32(unsigned int k) {
    return __uint_as_float((k & 0x80000000u) ? (k & 0x7fffffffu) : ~k);
}

// Pack B-fragments for both directions; init min-keys and out.
__global__ __launch_bounds__(256) void chamfer_prep(
    const float* __restrict__ pred, const float* __restrict__ gt,
    unsigned short* __restrict__ bpack, unsigned int* __restrict__ keys,
    float* __restrict__ out)
{
    const int i   = blockIdx.x * 256 + threadIdx.x;  // 0 .. 2*B*N-1
    if (i == 0) out[0] = 0.0f;
    keys[i] = 0xFFFFFFFFu;
    const int dir = i >> 16;
    const int bm  = i & 0xFFFF;                      // b*N + m
    const float* dst = dir ? pred : gt;
    const float x = dst[3*bm+0], y = dst[3*bm+1], z = dst[3*bm+2];
    const unsigned short hx = bf16_rne(x), hy = bf16_rne(y), hz = bf16_rne(z);
    const unsigned short lx = bf16_rne(x - bf16f(hx));
    const unsigned short ly = bf16_rne(y - bf16f(hy));
    const unsigned short lz = bf16_rne(z - bf16f(hz));
    const float gn = x*x + y*y + z*z;
    const unsigned short gnh = bf16_rne(gn), gnl = bf16_rne(gn - bf16f(gnh));
    const unsigned short one = 0x3F80;

    const int b  = bm >> 13, m = bm & (N_DIM - 1);
    const int mt = m >> 5,   c = m & 31;
    const int dirb = (dir << 3) | b;
    unsigned short* p0 = bpack + ((size_t)(dirb * MT + mt) * 64 + c) * 8;
    unsigned short* p1 = p0 + 32 * 8;
    // half0 = k0..7 : gh(xyz) gl(xyz) gh(x,y) ; half1 = k8..15 : gh(z) 1 1 gnh gnl 0 0 0
    bf16x8 h0 = {(short)hx,(short)hy,(short)hz,(short)lx,(short)ly,(short)lz,(short)hx,(short)hy};
    bf16x8 h1 = {(short)hz,(short)one,(short)one,(short)gnh,(short)gnl,0,0,0};
    *(bf16x8*)p0 = h0;
    *(bf16x8*)p1 = h1;
}

__global__ __launch_bounds__(BLOCK, 4) void chamfer_partial(
    const float* __restrict__ pred, const float* __restrict__ gt,
    const bf16x8* __restrict__ bpack, unsigned int* __restrict__ keys)
{
    __shared__ bf16x8 sbuf[2][CH * 64];     // 2 x 16 KB double buffer
    const int dirb = blockIdx.x;            // low grid bits -> stream/XCD L2 locality
    const int dir  = dirb >> 3, b = dirb & 7;
    const int w    = threadIdx.x >> 6, lane = threadIdx.x & 63;
    const int half = lane >> 5,  col = lane & 31;
    const int ms   = blockIdx.z;            // m-split index

    const float* src  = dir ? gt : pred;
    const float* srcb = src + (size_t)b * N_DIM * 3;

    // A fragments for this wave's PPW n-tiles (row = col, k-half = half).
    bf16x8 afrag[PPW];
    int ntile[PPW];
    #pragma unroll
    for (int p = 0; p < PPW; ++p) {
        ntile[p] = (blockIdx.y * 4 + w) * PPW + p;
        const int n = ntile[p] * 32 + col;
        const float x = srcb[3*n+0], y = srcb[3*n+1], z = srcb[3*n+2];
        const float ax = -2.f*x, ay = -2.f*y, az = -2.f*z;
        const unsigned short ahx = bf16_rne(ax), ahy = bf16_rne(ay), ahz = bf16_rne(az);
        const unsigned short alx = bf16_rne(ax - bf16f(ahx));
        const unsigned short aly = bf16_rne(ay - bf16f(ahy));
        const unsigned short alz = bf16_rne(az - bf16f(ahz));
        const float pn = x*x + y*y + z*z;
        const unsigned short pnh = bf16_rne(pn), pnl = bf16_rne(pn - bf16f(pnh));
        const unsigned short one = 0x3F80;
        bf16x8 a0 = {(short)ahx,(short)ahy,(short)ahz,(short)ahx,(short)ahy,(short)ahz,(short)alx,(short)aly};
        bf16x8 a1 = {(short)alz,(short)pnh,(short)pnl,(short)one,(short)one,0,0,0};
        afrag[p] = (half == 0) ? a0 : a1;
    }

    // This block's half of the B-fragment stream.
    const bf16x8* bp = bpack + (size_t)dirb * MT * 64 + (size_t)ms * MTB * 64;
    const f32x16 czero = {0.f,0.f,0.f,0.f,0.f,0.f,0.f,0.f,
                          0.f,0.f,0.f,0.f,0.f,0.f,0.f,0.f};
    float best[PPW][16];
    #pragma unroll
    for (int p = 0; p < PPW; ++p)
        #pragma unroll
        for (int r = 0; r < 16; ++r) best[p][r] = 1e30f;

    // async staging: wave w ferries frags [w*256 .. w*256+255] of each chunk,
    // 4 x global_load_lds (64 lanes x 16B = 1KB each), wave-uniform LDS base.
    #define GLL(c, pb) { \
        _Pragma("unroll") for (int i = 0; i < 4; ++i) { \
            const bf16x8* g = bp + (size_t)(c) * (CH*64) + w*256 + i*64 + lane; \
            __builtin_amdgcn_global_load_lds( \
                (const __attribute__((address_space(1))) void*)g, \
                (__attribute__((address_space(3))) void*)&sbuf[pb][w*256 + i*64], \
                16, 0, 0); \
        } }

    GLL(0, 0);
    __syncthreads();

    for (int c = 0; c < NC; ++c) {
        const int pb = c & 1;
        if (c + 1 < NC) GLL(c + 1, pb ^ 1);
        #pragma unroll
        for (int j = 0; j < CH; j += 2) {
            const bf16x8 b0 = sbuf[pb][(j  ) * 64 + lane];
            const bf16x8 b1 = sbuf[pb][(j+1) * 64 + lane];
            #pragma unroll
            for (int p = 0; p < PPW; ++p) {
                f32x16 d0 = __builtin_amdgcn_mfma_f32_32x32x16_bf16(afrag[p], b0, czero, 0, 0, 0);
                f32x16 d1 = __builtin_amdgcn_mfma_f32_32x32x16_bf16(afrag[p], b1, czero, 0, 0, 0);
                #pragma unroll
                for (int r = 0; r < 16; ++r)
                    best[p][r] = fminf(fminf(best[p][r], d0[r]), d1[r]);  // v_min3
            }
        }
        __syncthreads();
    }

    // Min across the 32 lanes of each half, then atomicMin-merge across MSPLIT.
    unsigned int* kb = keys + (size_t)dirb * N_DIM;
    #pragma unroll
    for (int p = 0; p < PPW; ++p) {
        #pragma unroll
        for (int r = 0; r < 16; ++r) {
            float v = best[p][r];
            v = fminf(v, __shfl_xor(v, 1,  64));
            v = fminf(v, __shfl_xor(v, 2,  64));
            v = fminf(v, __shfl_xor(v, 4,  64));
            v = fminf(v, __shfl_xor(v, 8,  64));
            v = fminf(v, __shfl_xor(v, 16, 64));
            const int row = (r & 3) + 8 * (r >> 2) + 4 * half;
            if (col == r)
                atomicMin(&kb[ntile[p] * 32 + row], f32_to_ordered_u32(v));
        }
    }
}

__global__ __launch_bounds__(256) void chamfer_reduce(
    const unsigned int* __restrict__ keys, float* __restrict__ out)
{
    const float scale = 100.0f * 0.5f / ((float)B_DIM * (float)N_DIM);
    const int i = (blockIdx.x * 256 + threadIdx.x) * 4;
    const uint4 k = *(const uint4*)(keys + i);
    float s = ordered_u32_to_f32(k.x) + ordered_u32_to_f32(k.y)
            + ordered_u32_to_f32(k.z) + ordered_u32_to_f32(k.w);
    for (int off = 32; off > 0; off >>= 1) s += __shfl_down(s, off, 64);
    __shared__ float wsum[4];
    if ((threadIdx.x & 63) == 0) wsum[threadIdx.x >> 6] = s;
    __syncthreads();
    if (threadIdx.x == 0)
        atomicAdd(out, (wsum[0] + wsum[1] + wsum[2] + wsum[3]) * scale);
}

extern "C" void kernel_launch(void* const* d_in, const int* in_sizes, int n_in,
                              void* d_out, int out_size, void* d_ws, size_t ws_size,
                              hipStream_t stream) {
    const float* pred = (const float*)d_in[0];
    const float* gt   = (const float*)d_in[1];
    float* out = (float*)d_out;
    // ws: [0, 4MiB) packed B-fragments ; [4MiB, 4.5MiB) ordered-u32 min keys
    unsigned short* bpack = (unsigned short*)d_ws;
    unsigned int* keys = (unsigned int*)((char*)d_ws + (size_t)16 * MT * 64 * 16);

    chamfer_prep<<<(2 * B_DIM * N_DIM) / 256, 256, 0, stream>>>(pred, gt, bpack, keys, out);

    // dirb x n-chunks(256 pts) x m-split = 16 x 32 x 2 = 1024 blocks, 4/CU
    dim3 grid(16, N_DIM / (32 * 4 * PPW), MSPLIT);
    chamfer_partial<<<grid, BLOCK, 0, stream>>>(pred, gt, (const bf16x8*)bpack, keys);

    chamfer_reduce<<<(2 * B_DIM * N_DIM) / (256 * 4), 256, 0, stream>>>(keys, out);
}